// Round 12
// baseline (734.501 us; speedup 1.0000x reference)
//
#include <hip/hip_runtime.h>
#include <math.h>

#define B_ 32
#define INLEN 10
#define LIN_ 16384
#define NPOLY 12
#define MM 6
#define CH 20
#define NB 4
#define RECEPT 25
#define L0 16434      // length after first conv
#define TTILE 216     // outputs per tile (multiple of 6) [R12: back to proven R7 tile]
#define NW 37         // TTILE/6 + 1 windows
#define XS_LEN 228    // TTILE + 12 halo
#define XS_PAD 229    // odd stride -> bank-conflict-free strided reads
#define GS_LEN 218    // TTILE + 2 gelu positions
#define LXS_PAD 122   // EVEN stride: 8B-aligns every lxs row for float2 (b64) reads.
                      // wl-stride 122 dwords -> 26*delta mod 32 distinct for delta 0..10 (no conflicts)
#define CCHUNK 5      // ci-chunk in stages B/D (R5 spill fix; caps live window regs)
#define COH 10        // output channels per 256-thread half (CH/2)

__device__ __forceinline__ float gelu_exact(float x) {
    return 0.5f * x * (1.0f + erff(x * 0.70710678118654752440f));
}

// ---------------- first conv: (B,10,16384) wrap-padded -> (B,20,16434) ----------------
__global__ void k_first(const float* __restrict__ in, const float* __restrict__ wf,
                        float* __restrict__ out) {
    int t = blockIdx.x * blockDim.x + threadIdx.x;
    int b = blockIdx.y;
    if (t >= L0) return;
    const float* inb = in + (size_t)b * INLEN * LIN_;
    float xw[INLEN][3];
#pragma unroll
    for (int ci = 0; ci < INLEN; ++ci) {
#pragma unroll
        for (int k = 0; k < 3; ++k) {
            int idx = t + k - RECEPT;
            idx = (idx < 0) ? idx + LIN_ : (idx >= LIN_ ? idx - LIN_ : idx);
            xw[ci][k] = inb[ci * LIN_ + idx];
        }
    }
    float* outb = out + (size_t)b * CH * L0;
#pragma unroll
    for (int co = 0; co < CH; ++co) {
        float acc = 0.f;
#pragma unroll
        for (int ci = 0; ci < INLEN; ++ci)
#pragma unroll
            for (int k = 0; k < 3; ++k)
                acc = fmaf(xw[ci][k], wf[(co * INLEN + ci) * 3 + k], acc);
        outb[(size_t)co * L0 + t] = acc;
    }
}

// ---------------- fused block: residual conv path + Legendre multiwavelet path ----------------
// R12 = R7 base (proven 108 us/dispatch) + LDS INSTRUCTION-COUNT REDUCTION:
//  - stage D rec: m-outer with float2 (b64) lxs reads -> 120 scalar ds_read_b32 become
//    60 b64 (old co-outer/m-inner made stride-20 reads the compiler can't merge);
//  - stage C2: float2 reads/writes (12+6 scalar -> 6+3 vector).
// R11 post-mortem: at 512 threads residency pins at ~2 blocks/CU regardless of LDS
// (39.4K->2.28, 31.7K->2.0) -> tile-shrink reverted; attack instruction count instead.
// Lessons kept: __launch_bounds__(512,2) only; CCHUNK=5 + unroll 1 (R5 LICM spills);
// readfirstlane'd cob (R6: weight reads stay s_load); odd XS stride.
__global__ __launch_bounds__(512, 2)
void k_block(const float* __restrict__ x, float* __restrict__ xn,
             const float* __restrict__ wA, const float* __restrict__ wB,
             const float* __restrict__ linm, const float* __restrict__ fd,
             const float* __restrict__ fr, int l) {
    const int lout = l - 12;
    const int tid  = threadIdx.x;          // 0..511
    const int t    = tid & 255;            // position within half
    const int half = __builtin_amdgcn_readfirstlane(tid >> 8);
    const int cob  = half * COH;           // SGPR: first output channel of this half
    const int t0   = blockIdx.x * TTILE;   // multiple of 6
    const int b    = blockIdx.y;

    // per-half weight bases off the SGPR cob -> scalar loads inside B/D
    const float* wAh = wA + cob * CH * 3;
    const float* wBh = wB + cob * CH * 3;

    __shared__ float xs[CH][XS_PAD];       // x tile; after C1+B, reused as gs tile
    __shared__ float lxs[NW][LXS_PAD];     // Legendre coeffs, layout [wl][u], u = m*20+c
    __shared__ float lm_s[CH * MM * MM];   // lin_m[i] : [g][o][i]
    __shared__ float fr_s[MM * NPOLY];     // filt_r

    const float* xb = x + (size_t)b * CH * l;

    for (int i = tid; i < CH * MM * MM; i += 512) lm_s[i] = linm[i];
    for (int i = tid; i < MM * NPOLY; i += 512)   fr_s[i] = fr[i];

    // stage A: load x tile (zero-fill past end; those outputs are masked)
    for (int i = tid; i < CH * XS_LEN; i += 512) {
        int c = i / XS_LEN, p = i - c * XS_LEN;
        int gp = t0 + p;
        xs[c][p] = (gp < l) ? xb[(size_t)c * l + gp] : 0.f;
    }
    __syncthreads();

    // stage C1: Legendre decomposition per (window, channel): Lx[m] = sum_k x[6wl+k]*fd[m][k]/2
    for (int item = tid; item < NW * CH; item += 512) {
        int wl = item / CH, c = item - wl * CH;
        float xv[NPOLY];
#pragma unroll
        for (int k = 0; k < NPOLY; ++k) xv[k] = xs[c][6 * wl + k];
#pragma unroll
        for (int m = 0; m < MM; ++m) {
            float acc = 0.f;
#pragma unroll
            for (int k = 0; k < NPOLY; ++k)
                acc = fmaf(xv[k], fd[m * NPOLY + k], acc);
            lxs[wl][m * CH + c] = acc * 0.5f;
        }
    }

    // stage B: this half computes gelu(conv_a(x)) for its 10 output channels, ci chunked
    float gv[COH];
    if (t < GS_LEN) {
#pragma unroll
        for (int co = 0; co < COH; ++co) gv[co] = 0.f;
#pragma unroll 1
        for (int cig = 0; cig < CH; cig += CCHUNK) {
            float xw[CCHUNK][3];
#pragma unroll
            for (int j = 0; j < CCHUNK; ++j) {
                xw[j][0] = xs[cig + j][t + 4];
                xw[j][1] = xs[cig + j][t + 5];
                xw[j][2] = xs[cig + j][t + 6];
            }
#pragma unroll
            for (int co = 0; co < COH; ++co) {
                float acc = gv[co];
#pragma unroll
                for (int j = 0; j < CCHUNK; ++j)
#pragma unroll
                    for (int k = 0; k < 3; ++k)
                        acc = fmaf(xw[j][k], wAh[(co * CH + cig + j) * 3 + k], acc);
                gv[co] = acc;
            }
        }
#pragma unroll
        for (int co = 0; co < COH; ++co) gv[co] = gelu_exact(gv[co]);
    }
    __syncthreads();   // all reads of xs (C1 + B) complete block-wide

    // write g into the dead xs region (each half writes its 10 rows; cob is SGPR)
    if (t < GS_LEN) {
#pragma unroll
        for (int co = 0; co < COH; ++co) xs[cob + co][t] = gv[co];
    }

    // stage C2: grouped mode mixing on flattened mode-major index u = m*20+c,
    // groups are 6-consecutive u's -> float2-vectorized (group g = float2 idx 3g..3g+2)
    for (int item = tid; item < NW * CH; item += 512) {
        int wl = item / CH, g = item - wl * CH;
        float2* row = reinterpret_cast<float2*>(&lxs[wl][0]);   // row base 8B-aligned (even pad)
        float2 v0 = row[g * 3 + 0];
        float2 v1 = row[g * 3 + 1];
        float2 v2 = row[g * 3 + 2];
        float iv[MM] = {v0.x, v0.y, v1.x, v1.y, v2.x, v2.y};
        float ov[MM];
#pragma unroll
        for (int o = 0; o < MM; ++o) {
            float acc = 0.f;
#pragma unroll
            for (int i = 0; i < MM; ++i)
                acc = fmaf(iv[i], lm_s[(g * MM + o) * MM + i], acc);
            ov[o] = acc;
        }
        row[g * 3 + 0] = make_float2(ov[0], ov[1]);
        row[g * 3 + 1] = make_float2(ov[2], ov[3]);
        row[g * 3 + 2] = make_float2(ov[4], ov[5]);
    }
    __syncthreads();

    // stage D: out[t'] = gelu( rec[t'+6] + conv_b(g)[t'+4] ) for this half's 10 channels
    if (t < TTILE && t0 + t < lout) {
        const int tp = t;
        float acc[COH];
#pragma unroll
        for (int co = 0; co < COH; ++co) acc[co] = 0.f;
#pragma unroll 1
        for (int cig = 0; cig < CH; cig += CCHUNK) {
            float aw[CCHUNK][3];
#pragma unroll
            for (int j = 0; j < CCHUNK; ++j) {
                aw[j][0] = xs[cig + j][tp];
                aw[j][1] = xs[cig + j][tp + 1];
                aw[j][2] = xs[cig + j][tp + 2];
            }
#pragma unroll
            for (int co = 0; co < COH; ++co) {
                float a = acc[co];
#pragma unroll
                for (int j = 0; j < CCHUNK; ++j)
#pragma unroll
                    for (int k = 0; k < 3; ++k)
                        a = fmaf(aw[j][k], wBh[(co * CH + cig + j) * 3 + k], a);
                acc[co] = a;
            }
        }
        const int r1  = tp % 6;        // (t0+tp+6) % 6
        const int wl1 = tp / 6 + 1;    // local window (t'+6)/6, <= 36 < NW
        float frA[MM], frB[MM];
#pragma unroll
        for (int m = 0; m < MM; ++m) {
            frA[m] = fr_s[m * NPOLY + r1];
            frB[m] = fr_s[m * NPOLY + r1 + 6];
        }
        // rec via m-outer float2 loads: lxs[wl][cob + m*20 + {2j,2j+1}], 8B-aligned
        // (row base = wl*122 floats = 488B, cob*4 = 0 or 40 -> both 0 mod 8)
        float rec[COH];
#pragma unroll
        for (int co = 0; co < COH; ++co) rec[co] = 0.f;
        {
            const float2* pA = reinterpret_cast<const float2*>(&lxs[wl1][cob]);
            const float2* pB = reinterpret_cast<const float2*>(&lxs[wl1 - 1][cob]);
#pragma unroll
            for (int m = 0; m < MM; ++m) {
                const float fA = frA[m], fB = frB[m];
#pragma unroll
                for (int j = 0; j < COH / 2; ++j) {
                    float2 a  = pA[m * (CH / 2) + j];
                    float2 bq = pB[m * (CH / 2) + j];
                    rec[2 * j]     = fmaf(a.x, fA, fmaf(bq.x, fB, rec[2 * j]));
                    rec[2 * j + 1] = fmaf(a.y, fA, fmaf(bq.y, fB, rec[2 * j + 1]));
                }
            }
        }
        float* xnb = xn + (size_t)b * CH * lout + (size_t)cob * lout;  // SGPR-uniform base
#pragma unroll
        for (int co = 0; co < COH; ++co)
            xnb[(size_t)co * lout + t0 + tp] = gelu_exact(acc[co] + rec[co]);
    }
}

// ---------------- final: gelu(20->128) -> 128->1, slice to 16384 ----------------
__global__ void k_final(const float* __restrict__ x, const float* __restrict__ w11,
                        const float* __restrict__ wout, float* __restrict__ out) {
    int t = blockIdx.x * blockDim.x + threadIdx.x;
    int b = blockIdx.y;
    if (t >= LIN_) return;
    const int l4 = L0 - NB * 12;   // 16386
    const float* xb = x + (size_t)b * CH * l4;
    float xv[CH];
#pragma unroll
    for (int c = 0; c < CH; ++c) xv[c] = xb[(size_t)c * l4 + t];
    float acc0 = 0.f, acc1 = 0.f, acc2 = 0.f, acc3 = 0.f;
    for (int h = 0; h < 128; h += 4) {
        float hv0 = 0.f, hv1 = 0.f, hv2 = 0.f, hv3 = 0.f;
#pragma unroll
        for (int c = 0; c < CH; ++c) {
            hv0 = fmaf(xv[c], w11[(h + 0) * CH + c], hv0);
            hv1 = fmaf(xv[c], w11[(h + 1) * CH + c], hv1);
            hv2 = fmaf(xv[c], w11[(h + 2) * CH + c], hv2);
            hv3 = fmaf(xv[c], w11[(h + 3) * CH + c], hv3);
        }
        acc0 = fmaf(gelu_exact(hv0), wout[h + 0], acc0);
        acc1 = fmaf(gelu_exact(hv1), wout[h + 1], acc1);
        acc2 = fmaf(gelu_exact(hv2), wout[h + 2], acc2);
        acc3 = fmaf(gelu_exact(hv3), wout[h + 3], acc3);
    }
    out[(size_t)b * LIN_ + t] = (acc0 + acc1) + (acc2 + acc3);
}

extern "C" void kernel_launch(void* const* d_in, const int* in_sizes, int n_in,
                              void* d_out, int out_size, void* d_ws, size_t ws_size,
                              hipStream_t stream) {
    const float* input   = (const float*)d_in[0];
    const float* w_first = (const float*)d_in[1];
    const float* conv_a  = (const float*)d_in[2];
    const float* conv_b  = (const float*)d_in[3];
    const float* lin_m   = (const float*)d_in[4];
    const float* w11     = (const float*)d_in[5];
    const float* w_out   = (const float*)d_in[6];
    const float* filt_d  = (const float*)d_in[7];
    const float* filt_r  = (const float*)d_in[8];
    float* out = (float*)d_out;

    const size_t bufElems = (size_t)B_ * CH * L0;   // 42.07 MB
    float* xA = (float*)d_ws;
    float* xB = xA + bufElems;

    {
        dim3 grid((L0 + 255) / 256, B_);
        k_first<<<grid, 256, 0, stream>>>(input, w_first, xA);
    }

    int l = L0;
    float* cur = xA;
    float* nxt = xB;
    for (int i = 0; i < NB; ++i) {
        int lout  = l - 12;
        int tiles = (lout + TTILE - 1) / TTILE;
        dim3 grid(tiles, B_);
        k_block<<<grid, 512, 0, stream>>>(cur, nxt,
                                          conv_a + i * CH * CH * 3,
                                          conv_b + i * CH * CH * 3,
                                          lin_m + i * CH * MM * MM,
                                          filt_d, filt_r, l);
        float* tswap = cur; cur = nxt; nxt = tswap;
        l = lout;
    }

    {
        dim3 grid((LIN_ + 255) / 256, B_);
        k_final<<<grid, 256, 0, stream>>>(cur, w11, w_out, out);
    }
}

// Round 13
// 495.262 us; speedup vs baseline: 1.4831x; 1.4831x over previous
//
#include <hip/hip_runtime.h>
#include <math.h>

#define B_ 32
#define INLEN 10
#define LIN_ 16384
#define NPOLY 12
#define MM 6
#define CH 20
#define NB 4
#define RECEPT 25
#define L0 16434      // length after first conv
#define TTILE 252     // outputs per tile (multiple of 6) [R13: 216->252, utilization tune]
#define NW 43         // TTILE/6 + 1 windows
#define XS_LEN 264    // TTILE + 12 halo
#define XS_PAD 265    // odd stride -> bank-conflict-free strided reads
#define GS_LEN 254    // TTILE + 2 gelu positions
#define LXS_PAD 121   // odd stride (121 mod 32 = 25, coprime with 32)
#define CCHUNK 5      // ci-chunk in stages B/D (R5 spill fix; caps live window regs)
#define COH 10        // output channels per 256-thread half (CH/2)

__device__ __forceinline__ float gelu_exact(float x) {
    return 0.5f * x * (1.0f + erff(x * 0.70710678118654752440f));
}

// ---------------- first conv: (B,10,16384) wrap-padded -> (B,20,16434) ----------------
__global__ void k_first(const float* __restrict__ in, const float* __restrict__ wf,
                        float* __restrict__ out) {
    int t = blockIdx.x * blockDim.x + threadIdx.x;
    int b = blockIdx.y;
    if (t >= L0) return;
    const float* inb = in + (size_t)b * INLEN * LIN_;
    float xw[INLEN][3];
#pragma unroll
    for (int ci = 0; ci < INLEN; ++ci) {
#pragma unroll
        for (int k = 0; k < 3; ++k) {
            int idx = t + k - RECEPT;
            idx = (idx < 0) ? idx + LIN_ : (idx >= LIN_ ? idx - LIN_ : idx);
            xw[ci][k] = inb[ci * LIN_ + idx];
        }
    }
    float* outb = out + (size_t)b * CH * L0;
#pragma unroll
    for (int co = 0; co < CH; ++co) {
        float acc = 0.f;
#pragma unroll
        for (int ci = 0; ci < INLEN; ++ci)
#pragma unroll
            for (int k = 0; k < 3; ++k)
                acc = fmaf(xw[ci][k], wf[(co * INLEN + ci) * 3 + k], acc);
        outb[(size_t)co * L0 + t] = acc;
    }
}

// ---------------- fused block: residual conv path + Legendre multiwavelet path ----------------
// R13 = R7 code verbatim (proven 108 us/dispatch, VGPR 20) with TTILE 216->252.
// R12 POST-MORTEM: float2 rec restructure pushed VGPR 20->72, crossing the 64-VGPR
// waves/SIMD cliff -> occ 57->22.5%, dur +46%. HARD CONSTRAINT: VGPR <= 64 here; the
// low-register co-outer scalar-rec form is the only proven-clean one. This round tunes
// utilization only: B active threads 218->254 of 256, D 216->252; blocks/dispatch -14%.
// Lessons kept: __launch_bounds__(512,2) only (over-hinting spills, R2/R3); CCHUNK=5 +
// unroll 1 (R5 LICM spills); readfirstlane'd cob (R6: weight reads stay s_load);
// odd LDS strides (R5); no fusion (R8/R10 residency collapse).
__global__ __launch_bounds__(512, 2)
void k_block(const float* __restrict__ x, float* __restrict__ xn,
             const float* __restrict__ wA, const float* __restrict__ wB,
             const float* __restrict__ linm, const float* __restrict__ fd,
             const float* __restrict__ fr, int l) {
    const int lout = l - 12;
    const int tid  = threadIdx.x;          // 0..511
    const int t    = tid & 255;            // position within half
    const int half = __builtin_amdgcn_readfirstlane(tid >> 8);
    const int cob  = half * COH;           // SGPR: first output channel of this half
    const int t0   = blockIdx.x * TTILE;   // multiple of 6
    const int b    = blockIdx.y;

    // per-half weight bases off the SGPR cob -> scalar loads inside B/D
    const float* wAh = wA + cob * CH * 3;
    const float* wBh = wB + cob * CH * 3;

    __shared__ float xs[CH][XS_PAD];       // x tile; after C1+B, reused as gs tile
    __shared__ float lxs[NW][LXS_PAD];     // Legendre coeffs, layout [wl][u], u = m*20+c
    __shared__ float lm_s[CH * MM * MM];   // lin_m[i] : [g][o][i]
    __shared__ float fr_s[MM * NPOLY];     // filt_r

    const float* xb = x + (size_t)b * CH * l;

    for (int i = tid; i < CH * MM * MM; i += 512) lm_s[i] = linm[i];
    for (int i = tid; i < MM * NPOLY; i += 512)   fr_s[i] = fr[i];

    // stage A: load x tile (zero-fill past end; those outputs are masked)
    for (int i = tid; i < CH * XS_LEN; i += 512) {
        int c = i / XS_LEN, p = i - c * XS_LEN;
        int gp = t0 + p;
        xs[c][p] = (gp < l) ? xb[(size_t)c * l + gp] : 0.f;
    }
    __syncthreads();

    // stage C1: Legendre decomposition per (window, channel): Lx[m] = sum_k x[6wl+k]*fd[m][k]/2
    for (int item = tid; item < NW * CH; item += 512) {
        int wl = item / CH, c = item - wl * CH;
        float xv[NPOLY];
#pragma unroll
        for (int k = 0; k < NPOLY; ++k) xv[k] = xs[c][6 * wl + k];
#pragma unroll
        for (int m = 0; m < MM; ++m) {
            float acc = 0.f;
#pragma unroll
            for (int k = 0; k < NPOLY; ++k)
                acc = fmaf(xv[k], fd[m * NPOLY + k], acc);
            lxs[wl][m * CH + c] = acc * 0.5f;
        }
    }

    // stage B: this half computes gelu(conv_a(x)) for its 10 output channels, ci chunked
    float gv[COH];
    if (t < GS_LEN) {
#pragma unroll
        for (int co = 0; co < COH; ++co) gv[co] = 0.f;
#pragma unroll 1
        for (int cig = 0; cig < CH; cig += CCHUNK) {
            float xw[CCHUNK][3];
#pragma unroll
            for (int j = 0; j < CCHUNK; ++j) {
                xw[j][0] = xs[cig + j][t + 4];
                xw[j][1] = xs[cig + j][t + 5];
                xw[j][2] = xs[cig + j][t + 6];
            }
#pragma unroll
            for (int co = 0; co < COH; ++co) {
                float acc = gv[co];
#pragma unroll
                for (int j = 0; j < CCHUNK; ++j)
#pragma unroll
                    for (int k = 0; k < 3; ++k)
                        acc = fmaf(xw[j][k], wAh[(co * CH + cig + j) * 3 + k], acc);
                gv[co] = acc;
            }
        }
#pragma unroll
        for (int co = 0; co < COH; ++co) gv[co] = gelu_exact(gv[co]);
    }
    __syncthreads();   // all reads of xs (C1 + B) complete block-wide

    // write g into the dead xs region (each half writes its 10 rows; cob is SGPR)
    if (t < GS_LEN) {
#pragma unroll
        for (int co = 0; co < COH; ++co) xs[cob + co][t] = gv[co];
    }

    // stage C2: grouped mode mixing on flattened mode-major index u = m*20+c,
    // groups are 6-consecutive u's (block-diagonal -> safe in place)
    for (int item = tid; item < NW * CH; item += 512) {
        int wl = item / CH, g = item - wl * CH;
        float iv[MM], ov[MM];
#pragma unroll
        for (int i = 0; i < MM; ++i) iv[i] = lxs[wl][g * MM + i];
#pragma unroll
        for (int o = 0; o < MM; ++o) {
            float acc = 0.f;
#pragma unroll
            for (int i = 0; i < MM; ++i)
                acc = fmaf(iv[i], lm_s[(g * MM + o) * MM + i], acc);
            ov[o] = acc;
        }
#pragma unroll
        for (int o = 0; o < MM; ++o) lxs[wl][g * MM + o] = ov[o];
    }
    __syncthreads();

    // stage D: out[t'] = gelu( rec[t'+6] + conv_b(g)[t'+4] ) for this half's 10 channels
    if (t < TTILE && t0 + t < lout) {
        const int tp = t;
        float acc[COH];
#pragma unroll
        for (int co = 0; co < COH; ++co) acc[co] = 0.f;
#pragma unroll 1
        for (int cig = 0; cig < CH; cig += CCHUNK) {
            float aw[CCHUNK][3];
#pragma unroll
            for (int j = 0; j < CCHUNK; ++j) {
                aw[j][0] = xs[cig + j][tp];
                aw[j][1] = xs[cig + j][tp + 1];
                aw[j][2] = xs[cig + j][tp + 2];
            }
#pragma unroll
            for (int co = 0; co < COH; ++co) {
                float a = acc[co];
#pragma unroll
                for (int j = 0; j < CCHUNK; ++j)
#pragma unroll
                    for (int k = 0; k < 3; ++k)
                        a = fmaf(aw[j][k], wBh[(co * CH + cig + j) * 3 + k], a);
                acc[co] = a;
            }
        }
        const int r1  = tp % 6;        // (t0+tp+6) % 6
        const int wl1 = tp / 6 + 1;    // local window (t'+6)/6, <= 42 < NW
        float frA[MM], frB[MM];
#pragma unroll
        for (int m = 0; m < MM; ++m) {
            frA[m] = fr_s[m * NPOLY + r1];
            frB[m] = fr_s[m * NPOLY + r1 + 6];
        }
        float* xnb = xn + (size_t)b * CH * lout + (size_t)cob * lout;  // SGPR-uniform base
#pragma unroll
        for (int co = 0; co < COH; ++co) {
            float rec = 0.f;
#pragma unroll
            for (int m = 0; m < MM; ++m) {
                rec = fmaf(lxs[wl1][m * CH + cob + co], frA[m], rec);
                rec = fmaf(lxs[wl1 - 1][m * CH + cob + co], frB[m], rec);
            }
            xnb[(size_t)co * lout + t0 + tp] = gelu_exact(acc[co] + rec);
        }
    }
}

// ---------------- final: gelu(20->128) -> 128->1, slice to 16384 ----------------
__global__ void k_final(const float* __restrict__ x, const float* __restrict__ w11,
                        const float* __restrict__ wout, float* __restrict__ out) {
    int t = blockIdx.x * blockDim.x + threadIdx.x;
    int b = blockIdx.y;
    if (t >= LIN_) return;
    const int l4 = L0 - NB * 12;   // 16386
    const float* xb = x + (size_t)b * CH * l4;
    float xv[CH];
#pragma unroll
    for (int c = 0; c < CH; ++c) xv[c] = xb[(size_t)c * l4 + t];
    float acc0 = 0.f, acc1 = 0.f, acc2 = 0.f, acc3 = 0.f;
    for (int h = 0; h < 128; h += 4) {
        float hv0 = 0.f, hv1 = 0.f, hv2 = 0.f, hv3 = 0.f;
#pragma unroll
        for (int c = 0; c < CH; ++c) {
            hv0 = fmaf(xv[c], w11[(h + 0) * CH + c], hv0);
            hv1 = fmaf(xv[c], w11[(h + 1) * CH + c], hv1);
            hv2 = fmaf(xv[c], w11[(h + 2) * CH + c], hv2);
            hv3 = fmaf(xv[c], w11[(h + 3) * CH + c], hv3);
        }
        acc0 = fmaf(gelu_exact(hv0), wout[h + 0], acc0);
        acc1 = fmaf(gelu_exact(hv1), wout[h + 1], acc1);
        acc2 = fmaf(gelu_exact(hv2), wout[h + 2], acc2);
        acc3 = fmaf(gelu_exact(hv3), wout[h + 3], acc3);
    }
    out[(size_t)b * LIN_ + t] = (acc0 + acc1) + (acc2 + acc3);
}

extern "C" void kernel_launch(void* const* d_in, const int* in_sizes, int n_in,
                              void* d_out, int out_size, void* d_ws, size_t ws_size,
                              hipStream_t stream) {
    const float* input   = (const float*)d_in[0];
    const float* w_first = (const float*)d_in[1];
    const float* conv_a  = (const float*)d_in[2];
    const float* conv_b  = (const float*)d_in[3];
    const float* lin_m   = (const float*)d_in[4];
    const float* w11     = (const float*)d_in[5];
    const float* w_out   = (const float*)d_in[6];
    const float* filt_d  = (const float*)d_in[7];
    const float* filt_r  = (const float*)d_in[8];
    float* out = (float*)d_out;

    const size_t bufElems = (size_t)B_ * CH * L0;   // 42.07 MB
    float* xA = (float*)d_ws;
    float* xB = xA + bufElems;

    {
        dim3 grid((L0 + 255) / 256, B_);
        k_first<<<grid, 256, 0, stream>>>(input, w_first, xA);
    }

    int l = L0;
    float* cur = xA;
    float* nxt = xB;
    for (int i = 0; i < NB; ++i) {
        int lout  = l - 12;
        int tiles = (lout + TTILE - 1) / TTILE;
        dim3 grid(tiles, B_);
        k_block<<<grid, 512, 0, stream>>>(cur, nxt,
                                          conv_a + i * CH * CH * 3,
                                          conv_b + i * CH * CH * 3,
                                          lin_m + i * CH * MM * MM,
                                          filt_d, filt_r, l);
        float* tswap = cur; cur = nxt; nxt = tswap;
        l = lout;
    }

    {
        dim3 grid((LIN_ + 255) / 256, B_);
        k_final<<<grid, 256, 0, stream>>>(cur, w11, w_out, out);
    }
}

// Round 16
// 487.051 us; speedup vs baseline: 1.5081x; 1.0169x over previous
//
#include <hip/hip_runtime.h>
#include <math.h>

#define B_ 32
#define INLEN 10
#define LIN_ 16384
#define NPOLY 12
#define MM 6
#define CH 20
#define NB 4
#define RECEPT 25
#define L0 16434      // length after first conv
#define TTILE 252     // outputs per tile (multiple of 6) [proven R13]
#define NW 43         // TTILE/6 + 1 windows
#define XS_LEN 264    // TTILE + 12 halo
#define XS_PAD 265    // odd stride -> bank-conflict-free strided reads
#define GS_LEN 254    // TTILE + 2 gelu positions
#define LXS_PAD 121   // odd stride (121 mod 32 = 25, coprime with 32)
#define CCHUNK 5      // ci-chunk in conv stages (R5 spill fix; caps live window regs)
#define COH 10        // output channels per 256-thread half (CH/2)
#define INW 266       // input tile width for fused first conv (XS_LEN + 2)

__device__ __forceinline__ float gelu_exact(float x) {
    return 0.5f * x * (1.0f + erff(x * 0.70710678118654752440f));
}

// ---------------- fused block: residual conv + Legendre multiwavelet path ----------------
// R16 = R14 resubmitted verbatim (R14/R15 benches were broker-side container failures;
// the same error hit R9 with a completely different kernel -> not kernel-correlated).
//   MODE 0: fuses k_first -- stage A loads RAW INPUT (10x266, wrap) into the dead lxs
//           region and computes the 3-tap first conv into xs. Kills k_first's 42 MB
//           write + layer-0's 42 MB read + one launch.
//   MODE 1: byte-identical to R13 k_block (layers 1,2; proven 96 us/dispatch, VGPR 40).
//   MODE 2: fuses k_final -- D keeps its output in regs, writes it to the dead xs
//           region; each half then computes 64 of 128 hidden units per position
//           (s_load weights via SGPR half base), partial sums meet in lxs, half 0
//           stores the final (B,1,16384). Kills k_final's 42 MB read + one launch;
//           this dispatch writes 2 MB instead of 42.
// NOT the R8/R10 fused-loop (residency collapse): each kernel stays straight-line,
// 3-5 barriers, layers 1-2 untouched. Lessons kept: __launch_bounds__(512,2) only;
// CCHUNK=5 + unroll 1 (R5 LICM spills); readfirstlane'd cob (R6: weights stay s_load);
// odd LDS strides; VGPR must stay <= 64 (R12 cliff).
template<int MODE>
__global__ __launch_bounds__(512, 2)
void k_block(const float* __restrict__ x, float* __restrict__ xn,
             const float* __restrict__ wA, const float* __restrict__ wB,
             const float* __restrict__ linm, const float* __restrict__ fd,
             const float* __restrict__ fr,
             const float* __restrict__ in0, const float* __restrict__ wf,
             const float* __restrict__ w11, const float* __restrict__ wout,
             int l) {
    const int lout = l - 12;
    const int tid  = threadIdx.x;          // 0..511
    const int t    = tid & 255;            // position within half
    const int half = __builtin_amdgcn_readfirstlane(tid >> 8);
    const int cob  = half * COH;           // SGPR: first output channel of this half
    const int t0   = blockIdx.x * TTILE;   // multiple of 6
    const int b    = blockIdx.y;

    const float* wAh = wA + cob * CH * 3;
    const float* wBh = wB + cob * CH * 3;

    __shared__ float xs[CH][XS_PAD];       // x tile; after C1+B, reused as gs tile
    __shared__ float lxs[NW][LXS_PAD];     // Legendre coeffs [wl][m*20+c]; also input
                                           // stage (MODE 0) / partial-sum buf (MODE 2)
    __shared__ float lm_s[CH * MM * MM];   // lin_m[i] : [g][o][i]
    __shared__ float fr_s[MM * NPOLY];     // filt_r

    for (int i = tid; i < CH * MM * MM; i += 512) lm_s[i] = linm[i];
    for (int i = tid; i < MM * NPOLY; i += 512)   fr_s[i] = fr[i];

    if constexpr (MODE == 0) {
        // stage A': raw input tile (wrap) into lxs region, then first conv -> xs
        float* inps = &lxs[0][0];                       // 10*266 = 2660 <= 43*121
        const float* inb = in0 + (size_t)b * INLEN * LIN_;
        for (int i = tid; i < INLEN * INW; i += 512) {
            int ci = i / INW, q = i - ci * INW;
            int gq = t0 + q - RECEPT;
            gq = (gq < 0) ? gq + LIN_ : (gq >= LIN_ ? gq - LIN_ : gq);
            inps[i] = inb[(size_t)ci * LIN_ + gq];
        }
        __syncthreads();
        const float* wfh = wf + cob * INLEN * 3;        // SGPR base -> s_load weights
        for (int p = t; p < XS_LEN; p += 256) {
            float acc[COH];
#pragma unroll
            for (int co = 0; co < COH; ++co) acc[co] = 0.f;
#pragma unroll 1
            for (int cig = 0; cig < INLEN; cig += CCHUNK) {
                float xw[CCHUNK][3];
#pragma unroll
                for (int j = 0; j < CCHUNK; ++j) {
                    xw[j][0] = inps[(cig + j) * INW + p];
                    xw[j][1] = inps[(cig + j) * INW + p + 1];
                    xw[j][2] = inps[(cig + j) * INW + p + 2];
                }
#pragma unroll
                for (int co = 0; co < COH; ++co) {
                    float a = acc[co];
#pragma unroll
                    for (int j = 0; j < CCHUNK; ++j)
#pragma unroll
                        for (int k = 0; k < 3; ++k)
                            a = fmaf(xw[j][k], wfh[(co * INLEN + cig + j) * 3 + k], a);
                    acc[co] = a;
                }
            }
            const bool live = (t0 + p < l);             // zero-fill past end (masked later)
#pragma unroll
            for (int co = 0; co < COH; ++co) xs[cob + co][p] = live ? acc[co] : 0.f;
        }
        __syncthreads();    // xs ready; inps (lxs region) now dead -> C1 may overwrite
    } else {
        // stage A: load x tile (zero-fill past end; those outputs are masked)
        const float* xb = x + (size_t)b * CH * l;
        for (int i = tid; i < CH * XS_LEN; i += 512) {
            int c = i / XS_LEN, p = i - c * XS_LEN;
            int gp = t0 + p;
            xs[c][p] = (gp < l) ? xb[(size_t)c * l + gp] : 0.f;
        }
        __syncthreads();
    }

    // stage C1: Legendre decomposition per (window, channel): Lx[m] = sum_k x[6wl+k]*fd[m][k]/2
    for (int item = tid; item < NW * CH; item += 512) {
        int wl = item / CH, c = item - wl * CH;
        float xv[NPOLY];
#pragma unroll
        for (int k = 0; k < NPOLY; ++k) xv[k] = xs[c][6 * wl + k];
#pragma unroll
        for (int m = 0; m < MM; ++m) {
            float acc = 0.f;
#pragma unroll
            for (int k = 0; k < NPOLY; ++k)
                acc = fmaf(xv[k], fd[m * NPOLY + k], acc);
            lxs[wl][m * CH + c] = acc * 0.5f;
        }
    }

    // stage B: this half computes gelu(conv_a(x)) for its 10 output channels, ci chunked
    float gv[COH];
    if (t < GS_LEN) {
#pragma unroll
        for (int co = 0; co < COH; ++co) gv[co] = 0.f;
#pragma unroll 1
        for (int cig = 0; cig < CH; cig += CCHUNK) {
            float xw[CCHUNK][3];
#pragma unroll
            for (int j = 0; j < CCHUNK; ++j) {
                xw[j][0] = xs[cig + j][t + 4];
                xw[j][1] = xs[cig + j][t + 5];
                xw[j][2] = xs[cig + j][t + 6];
            }
#pragma unroll
            for (int co = 0; co < COH; ++co) {
                float acc = gv[co];
#pragma unroll
                for (int j = 0; j < CCHUNK; ++j)
#pragma unroll
                    for (int k = 0; k < 3; ++k)
                        acc = fmaf(xw[j][k], wAh[(co * CH + cig + j) * 3 + k], acc);
                gv[co] = acc;
            }
        }
#pragma unroll
        for (int co = 0; co < COH; ++co) gv[co] = gelu_exact(gv[co]);
    }
    __syncthreads();   // all reads of xs (C1 + B) complete block-wide

    // write g into the dead xs region (each half writes its 10 rows; cob is SGPR)
    if (t < GS_LEN) {
#pragma unroll
        for (int co = 0; co < COH; ++co) xs[cob + co][t] = gv[co];
    }

    // stage C2: grouped mode mixing (6-consecutive-u groups, block-diagonal -> in place)
    for (int item = tid; item < NW * CH; item += 512) {
        int wl = item / CH, g = item - wl * CH;
        float iv[MM], ov[MM];
#pragma unroll
        for (int i = 0; i < MM; ++i) iv[i] = lxs[wl][g * MM + i];
#pragma unroll
        for (int o = 0; o < MM; ++o) {
            float acc = 0.f;
#pragma unroll
            for (int i = 0; i < MM; ++i)
                acc = fmaf(iv[i], lm_s[(g * MM + o) * MM + i], acc);
            ov[o] = acc;
        }
#pragma unroll
        for (int o = 0; o < MM; ++o) lxs[wl][g * MM + o] = ov[o];
    }
    __syncthreads();

    // stage D: out[t'] = gelu( rec[t'+6] + conv_b(g)[t'+4] ) for this half's 10 channels
    const bool vd = (t < TTILE) && (t0 + t < lout);
    float outv[COH];
    if (vd) {
        const int tp = t;
        float acc[COH];
#pragma unroll
        for (int co = 0; co < COH; ++co) acc[co] = 0.f;
#pragma unroll 1
        for (int cig = 0; cig < CH; cig += CCHUNK) {
            float aw[CCHUNK][3];
#pragma unroll
            for (int j = 0; j < CCHUNK; ++j) {
                aw[j][0] = xs[cig + j][tp];
                aw[j][1] = xs[cig + j][tp + 1];
                aw[j][2] = xs[cig + j][tp + 2];
            }
#pragma unroll
            for (int co = 0; co < COH; ++co) {
                float a = acc[co];
#pragma unroll
                for (int j = 0; j < CCHUNK; ++j)
#pragma unroll
                    for (int k = 0; k < 3; ++k)
                        a = fmaf(aw[j][k], wBh[(co * CH + cig + j) * 3 + k], a);
                acc[co] = a;
            }
        }
        const int r1  = tp % 6;        // (t0+tp+6) % 6
        const int wl1 = tp / 6 + 1;    // local window (t'+6)/6, <= 42 < NW
        float frA[MM], frB[MM];
#pragma unroll
        for (int m = 0; m < MM; ++m) {
            frA[m] = fr_s[m * NPOLY + r1];
            frB[m] = fr_s[m * NPOLY + r1 + 6];
        }
#pragma unroll
        for (int co = 0; co < COH; ++co) {
            float rec = 0.f;
#pragma unroll
            for (int m = 0; m < MM; ++m) {
                rec = fmaf(lxs[wl1][m * CH + cob + co], frA[m], rec);
                rec = fmaf(lxs[wl1 - 1][m * CH + cob + co], frB[m], rec);
            }
            outv[co] = gelu_exact(acc[co] + rec);
        }
        if constexpr (MODE != 2) {
            float* xnb = xn + (size_t)b * CH * lout + (size_t)cob * lout;
#pragma unroll
            for (int co = 0; co < COH; ++co)
                xnb[(size_t)co * lout + t0 + t] = outv[co];
        }
    }

    if constexpr (MODE == 2) {
        // fused final head: gelu(20->128) -> 128->1, sliced to 16384
        __syncthreads();   // all D reads of xs/lxs done
        if (vd) {
#pragma unroll
            for (int co = 0; co < COH; ++co) xs[cob + co][t] = outv[co];
        }
        __syncthreads();   // layer-3 output visible in xs
        const bool vf = (t < TTILE) && (t0 + t < LIN_);
        float* pb = &lxs[0][0];                    // lxs dead -> partial-sum buffer
        if (vf) {
            float xv[CH];
#pragma unroll
            for (int c = 0; c < CH; ++c) xv[c] = xs[c][t];
            const float* w11h  = w11 + (size_t)(half * 64) * CH;   // SGPR base
            const float* wouth = wout + half * 64;
            float partial = 0.f;
#pragma unroll 1
            for (int h = 0; h < 64; h += 2) {
                float hv0 = 0.f, hv1 = 0.f;
#pragma unroll
                for (int c = 0; c < CH; ++c) {
                    hv0 = fmaf(xv[c], w11h[h * CH + c], hv0);
                    hv1 = fmaf(xv[c], w11h[(h + 1) * CH + c], hv1);
                }
                partial = fmaf(gelu_exact(hv0), wouth[h], partial);
                partial = fmaf(gelu_exact(hv1), wouth[h + 1], partial);
            }
            pb[half * 256 + t] = partial;
        }
        __syncthreads();
        if (vf && half == 0)
            xn[(size_t)b * LIN_ + t0 + t] = pb[t] + pb[256 + t];
    }
}

extern "C" void kernel_launch(void* const* d_in, const int* in_sizes, int n_in,
                              void* d_out, int out_size, void* d_ws, size_t ws_size,
                              hipStream_t stream) {
    const float* input   = (const float*)d_in[0];
    const float* w_first = (const float*)d_in[1];
    const float* conv_a  = (const float*)d_in[2];
    const float* conv_b  = (const float*)d_in[3];
    const float* lin_m   = (const float*)d_in[4];
    const float* w11     = (const float*)d_in[5];
    const float* w_out   = (const float*)d_in[6];
    const float* filt_d  = (const float*)d_in[7];
    const float* filt_r  = (const float*)d_in[8];
    float* out = (float*)d_out;

    const size_t bufElems = (size_t)B_ * CH * L0;   // 42.07 MB
    float* xA = (float*)d_ws;
    float* xB = xA + bufElems;

    const int WSTEP = CH * CH * 3;
    const int MSTEP = CH * MM * MM;

    {
        dim3 grid((L0 - 12 + TTILE - 1) / TTILE, B_);
        k_block<0><<<grid, 512, 0, stream>>>(nullptr, xA, conv_a, conv_b, lin_m,
                                             filt_d, filt_r, input, w_first,
                                             nullptr, nullptr, L0);
    }
    {
        dim3 grid((L0 - 24 + TTILE - 1) / TTILE, B_);
        k_block<1><<<grid, 512, 0, stream>>>(xA, xB, conv_a + WSTEP, conv_b + WSTEP,
                                             lin_m + MSTEP, filt_d, filt_r,
                                             nullptr, nullptr, nullptr, nullptr, L0 - 12);
    }
    {
        dim3 grid((L0 - 36 + TTILE - 1) / TTILE, B_);
        k_block<1><<<grid, 512, 0, stream>>>(xB, xA, conv_a + 2 * WSTEP, conv_b + 2 * WSTEP,
                                             lin_m + 2 * MSTEP, filt_d, filt_r,
                                             nullptr, nullptr, nullptr, nullptr, L0 - 24);
    }
    {
        dim3 grid((LIN_ + TTILE - 1) / TTILE, B_);
        k_block<2><<<grid, 512, 0, stream>>>(xA, out, conv_a + 3 * WSTEP, conv_b + 3 * WSTEP,
                                             lin_m + 3 * MSTEP, filt_d, filt_r,
                                             nullptr, nullptr, w11, w_out, L0 - 36);
    }
}

// Round 17
// 473.566 us; speedup vs baseline: 1.5510x; 1.0285x over previous
//
#include <hip/hip_runtime.h>
#include <math.h>

#define B_ 32
#define INLEN 10
#define LIN_ 16384
#define NPOLY 12
#define MM 6
#define CH 20
#define RECEPT 25
#define L0 16434      // length after first conv
#define TT2 240       // final outputs per tile per pair-kernel (multiple of 6)
#define XS_LEN 264    // layer-A input width = TT2 + 24 (same as proven R13/R16 tile!)
#define XS_PAD 265    // odd stride -> bank-conflict-free strided reads
#define NWA 43        // (264-12)/6+1 windows, layer A
#define NWB 41        // (252-12)/6+1 windows, layer B
#define LXS_PAD 121   // odd stride
#define CCHUNK 5      // ci-chunk (R5 spill fix)
#define COH 10        // output channels per 256-thread half
#define INW 266       // raw-input tile width for fused first conv

__device__ __forceinline__ float gelu_exact(float x) {
    return 0.5f * x * (1.0f + erff(x * 0.70710678118654752440f));
}

// ---------------- pair kernel: 2 layers (+ first conv / + head) per dispatch ----------------
// R17: R16's boundary fusion extended to PAIR fusion -- 4 layer dispatches -> 2.
//   PAIR 0: first conv (proven MODE0 staging) + layer0 + layer1 -> writes 42 MB once.
//   PAIR 1: layer2 + layer3 + head (proven MODE2 tail) -> writes 2 MB.
// R16 lesson: fusion only saves TRAFFIC+LAUNCH (compute is conserved) -- this kills the
// remaining 2x84 MB round-trips + 2 stage-A staging passes + 2 launches.
// NOT R8's dynamic-N 4-layer loop (residency collapse): straight-line, compile-time
// constants, geometry = proven R13/R16 (XS_PAD 265, NWA 43, LDS 45.6K proven ~2 blk/CU
// at 51-56% occ). TT2=240 keeps every per-layer width <= 256 -> each thread holds at
// most ONE position's registers across a barrier (proven MODE2 pattern; VGPR stays < 64,
// the R12 cliff). Stale-column invariant: valid cone max col = LB_OUT-1+12 = LA_OUT-1,
// always vdA-valid (same invariant R8/R16 passed with).
// Lessons kept: __launch_bounds__(512,2) only; CCHUNK=5 + unroll 1; readfirstlane'd cob;
// odd LDS strides; lm_s reloaded between layers inside the writeback barrier gap.
template<int PAIR>
__global__ __launch_bounds__(512, 2)
void k_pair(const float* __restrict__ xin, float* __restrict__ xout,
            const float* __restrict__ conv_a, const float* __restrict__ conv_b,
            const float* __restrict__ lin_m, const float* __restrict__ fd,
            const float* __restrict__ fr,
            const float* __restrict__ in0, const float* __restrict__ wf,
            const float* __restrict__ w11, const float* __restrict__ wout) {
    constexpr int LA_IN  = (PAIR == 0) ? L0 : (L0 - 24);   // layer-A input length (global)
    constexpr int LA_OUT = LA_IN - 12;
    constexpr int LB_OUT = LA_OUT - 12;
    constexpr int WOFF   = CH * CH * 3;
    constexpr int MOFF   = CH * MM * MM;

    const int tid  = threadIdx.x;          // 0..511
    const int t    = tid & 255;            // position within half
    const int half = __builtin_amdgcn_readfirstlane(tid >> 8);
    const int cob  = half * COH;           // SGPR: first output channel of this half
    const int t0   = blockIdx.x * TT2;     // multiple of 6
    const int b    = blockIdx.y;

    const float* wAa = conv_a + (2 * PAIR)     * WOFF + cob * CH * 3;
    const float* wBa = conv_b + (2 * PAIR)     * WOFF + cob * CH * 3;
    const float* wAb = conv_a + (2 * PAIR + 1) * WOFF + cob * CH * 3;
    const float* wBb = conv_b + (2 * PAIR + 1) * WOFF + cob * CH * 3;

    __shared__ float xs[CH][XS_PAD];       // x -> g -> next x (in place, barrier-guarded)
    __shared__ float lxs[NWA][LXS_PAD];    // Legendre coeffs; also raw-input stage (PAIR0)
                                           // and head partial-sum buffer (PAIR1)
    __shared__ float lm_s[MOFF];           // current layer's lin_m
    __shared__ float fr_s[MM * NPOLY];     // filt_r (layer-invariant)

    for (int i = tid; i < MOFF; i += 512) lm_s[i] = lin_m[(2 * PAIR) * MOFF + i];
    for (int i = tid; i < MM * NPOLY; i += 512) fr_s[i] = fr[i];

    // ---------------- stage IN -> xs[0..264) ----------------
    if constexpr (PAIR == 0) {
        // raw input tile (wrap) into dead lxs region, then 3-tap first conv -> xs
        float* inps = &lxs[0][0];                       // 10*266 = 2660 <= 43*121
        const float* inb = in0 + (size_t)b * INLEN * LIN_;
        for (int i = tid; i < INLEN * INW; i += 512) {
            int ci = i / INW, q = i - ci * INW;
            int gq = t0 + q - RECEPT;
            gq = (gq < 0) ? gq + LIN_ : (gq >= LIN_ ? gq - LIN_ : gq);
            inps[i] = inb[(size_t)ci * LIN_ + gq];
        }
        __syncthreads();
        const float* wfh = wf + cob * INLEN * 3;        // SGPR base -> s_load weights
        for (int p = t; p < XS_LEN; p += 256) {
            float acc[COH];
#pragma unroll
            for (int co = 0; co < COH; ++co) acc[co] = 0.f;
#pragma unroll 1
            for (int cig = 0; cig < INLEN; cig += CCHUNK) {
                float xw[CCHUNK][3];
#pragma unroll
                for (int j = 0; j < CCHUNK; ++j) {
                    xw[j][0] = inps[(cig + j) * INW + p];
                    xw[j][1] = inps[(cig + j) * INW + p + 1];
                    xw[j][2] = inps[(cig + j) * INW + p + 2];
                }
#pragma unroll
                for (int co = 0; co < COH; ++co) {
                    float a = acc[co];
#pragma unroll
                    for (int j = 0; j < CCHUNK; ++j)
#pragma unroll
                        for (int k = 0; k < 3; ++k)
                            a = fmaf(xw[j][k], wfh[(co * INLEN + cig + j) * 3 + k], a);
                    acc[co] = a;
                }
            }
            const bool live = (t0 + p < L0);
#pragma unroll
            for (int co = 0; co < COH; ++co) xs[cob + co][p] = live ? acc[co] : 0.f;
        }
        __syncthreads();    // xs ready; inps region dead
    } else {
        const float* xb = xin + (size_t)b * CH * LA_IN;
        for (int i = tid; i < CH * XS_LEN; i += 512) {
            int c = i / XS_LEN, p = i - c * XS_LEN;
            int gp = t0 + p;
            xs[c][p] = (gp < LA_IN) ? xb[(size_t)c * LA_IN + gp] : 0.f;
        }
        __syncthreads();
    }

    float gv[COH];
    float outv[COH];

    // ================= LAYER A (input width 264) =================
    for (int item = tid; item < NWA * CH; item += 512) {        // C1
        int wl = item / CH, c = item - wl * CH;
        float xv[NPOLY];
#pragma unroll
        for (int k = 0; k < NPOLY; ++k) xv[k] = xs[c][6 * wl + k];
#pragma unroll
        for (int m = 0; m < MM; ++m) {
            float acc = 0.f;
#pragma unroll
            for (int k = 0; k < NPOLY; ++k)
                acc = fmaf(xv[k], fd[m * NPOLY + k], acc);
            lxs[wl][m * CH + c] = acc * 0.5f;
        }
    }
    if (t < XS_LEN - 10) {                                      // B (width 254)
#pragma unroll
        for (int co = 0; co < COH; ++co) gv[co] = 0.f;
#pragma unroll 1
        for (int cig = 0; cig < CH; cig += CCHUNK) {
            float xw[CCHUNK][3];
#pragma unroll
            for (int j = 0; j < CCHUNK; ++j) {
                xw[j][0] = xs[cig + j][t + 4];
                xw[j][1] = xs[cig + j][t + 5];
                xw[j][2] = xs[cig + j][t + 6];
            }
#pragma unroll
            for (int co = 0; co < COH; ++co) {
                float acc = gv[co];
#pragma unroll
                for (int j = 0; j < CCHUNK; ++j)
#pragma unroll
                    for (int k = 0; k < 3; ++k)
                        acc = fmaf(xw[j][k], wAa[(co * CH + cig + j) * 3 + k], acc);
                gv[co] = acc;
            }
        }
#pragma unroll
        for (int co = 0; co < COH; ++co) gv[co] = gelu_exact(gv[co]);
    }
    __syncthreads();
    if (t < XS_LEN - 10) {
#pragma unroll
        for (int co = 0; co < COH; ++co) xs[cob + co][t] = gv[co];
    }
    for (int item = tid; item < NWA * CH; item += 512) {        // C2
        int wl = item / CH, g = item - wl * CH;
        float iv[MM], ov[MM];
#pragma unroll
        for (int i = 0; i < MM; ++i) iv[i] = lxs[wl][g * MM + i];
#pragma unroll
        for (int o = 0; o < MM; ++o) {
            float acc = 0.f;
#pragma unroll
            for (int i = 0; i < MM; ++i)
                acc = fmaf(iv[i], lm_s[(g * MM + o) * MM + i], acc);
            ov[o] = acc;
        }
#pragma unroll
        for (int o = 0; o < MM; ++o) lxs[wl][g * MM + o] = ov[o];
    }
    __syncthreads();
    const bool vdA = (t < XS_LEN - 12) && (t0 + t < LA_OUT);    // D (252 outputs)
    if (vdA) {
        float acc[COH];
#pragma unroll
        for (int co = 0; co < COH; ++co) acc[co] = 0.f;
#pragma unroll 1
        for (int cig = 0; cig < CH; cig += CCHUNK) {
            float aw[CCHUNK][3];
#pragma unroll
            for (int j = 0; j < CCHUNK; ++j) {
                aw[j][0] = xs[cig + j][t];
                aw[j][1] = xs[cig + j][t + 1];
                aw[j][2] = xs[cig + j][t + 2];
            }
#pragma unroll
            for (int co = 0; co < COH; ++co) {
                float a = acc[co];
#pragma unroll
                for (int j = 0; j < CCHUNK; ++j)
#pragma unroll
                    for (int k = 0; k < 3; ++k)
                        a = fmaf(aw[j][k], wBa[(co * CH + cig + j) * 3 + k], a);
                acc[co] = a;
            }
        }
        const int r1  = t % 6;
        const int wl1 = t / 6 + 1;                              // <= 42 < NWA
        float frA[MM], frB[MM];
#pragma unroll
        for (int m = 0; m < MM; ++m) {
            frA[m] = fr_s[m * NPOLY + r1];
            frB[m] = fr_s[m * NPOLY + r1 + 6];
        }
#pragma unroll
        for (int co = 0; co < COH; ++co) {
            float rec = 0.f;
#pragma unroll
            for (int m = 0; m < MM; ++m) {
                rec = fmaf(lxs[wl1][m * CH + cob + co], frA[m], rec);
                rec = fmaf(lxs[wl1 - 1][m * CH + cob + co], frB[m], rec);
            }
            outv[co] = gelu_exact(acc[co] + rec);
        }
    }
    __syncthreads();               // all layer-A reads of xs/lxs done
    if (vdA) {
#pragma unroll
        for (int co = 0; co < COH; ++co) xs[cob + co][t] = outv[co];
    }
    for (int i = tid; i < MOFF; i += 512)                       // next layer's lin_m
        lm_s[i] = lin_m[(2 * PAIR + 1) * MOFF + i];
    __syncthreads();               // new x + lm visible

    // ================= LAYER B (input width 252) =================
    for (int item = tid; item < NWB * CH; item += 512) {        // C1
        int wl = item / CH, c = item - wl * CH;
        float xv[NPOLY];
#pragma unroll
        for (int k = 0; k < NPOLY; ++k) xv[k] = xs[c][6 * wl + k];
#pragma unroll
        for (int m = 0; m < MM; ++m) {
            float acc = 0.f;
#pragma unroll
            for (int k = 0; k < NPOLY; ++k)
                acc = fmaf(xv[k], fd[m * NPOLY + k], acc);
            lxs[wl][m * CH + c] = acc * 0.5f;
        }
    }
    if (t < XS_LEN - 22) {                                      // B (width 242)
#pragma unroll
        for (int co = 0; co < COH; ++co) gv[co] = 0.f;
#pragma unroll 1
        for (int cig = 0; cig < CH; cig += CCHUNK) {
            float xw[CCHUNK][3];
#pragma unroll
            for (int j = 0; j < CCHUNK; ++j) {
                xw[j][0] = xs[cig + j][t + 4];
                xw[j][1] = xs[cig + j][t + 5];
                xw[j][2] = xs[cig + j][t + 6];
            }
#pragma unroll
            for (int co = 0; co < COH; ++co) {
                float acc = gv[co];
#pragma unroll
                for (int j = 0; j < CCHUNK; ++j)
#pragma unroll
                    for (int k = 0; k < 3; ++k)
                        acc = fmaf(xw[j][k], wAb[(co * CH + cig + j) * 3 + k], acc);
                gv[co] = acc;
            }
        }
#pragma unroll
        for (int co = 0; co < COH; ++co) gv[co] = gelu_exact(gv[co]);
    }
    __syncthreads();
    if (t < XS_LEN - 22) {
#pragma unroll
        for (int co = 0; co < COH; ++co) xs[cob + co][t] = gv[co];
    }
    for (int item = tid; item < NWB * CH; item += 512) {        // C2
        int wl = item / CH, g = item - wl * CH;
        float iv[MM], ov[MM];
#pragma unroll
        for (int i = 0; i < MM; ++i) iv[i] = lxs[wl][g * MM + i];
#pragma unroll
        for (int o = 0; o < MM; ++o) {
            float acc = 0.f;
#pragma unroll
            for (int i = 0; i < MM; ++i)
                acc = fmaf(iv[i], lm_s[(g * MM + o) * MM + i], acc);
            ov[o] = acc;
        }
#pragma unroll
        for (int o = 0; o < MM; ++o) lxs[wl][g * MM + o] = ov[o];
    }
    __syncthreads();
    const bool vdB = (t < TT2) && (t0 + t < LB_OUT);            // D (240 outputs)
    if (vdB) {
        float acc[COH];
#pragma unroll
        for (int co = 0; co < COH; ++co) acc[co] = 0.f;
#pragma unroll 1
        for (int cig = 0; cig < CH; cig += CCHUNK) {
            float aw[CCHUNK][3];
#pragma unroll
            for (int j = 0; j < CCHUNK; ++j) {
                aw[j][0] = xs[cig + j][t];
                aw[j][1] = xs[cig + j][t + 1];
                aw[j][2] = xs[cig + j][t + 2];
            }
#pragma unroll
            for (int co = 0; co < COH; ++co) {
                float a = acc[co];
#pragma unroll
                for (int j = 0; j < CCHUNK; ++j)
#pragma unroll
                    for (int k = 0; k < 3; ++k)
                        a = fmaf(aw[j][k], wBb[(co * CH + cig + j) * 3 + k], a);
                acc[co] = a;
            }
        }
        const int r1  = t % 6;
        const int wl1 = t / 6 + 1;                              // <= 40 < NWB
        float frA[MM], frB[MM];
#pragma unroll
        for (int m = 0; m < MM; ++m) {
            frA[m] = fr_s[m * NPOLY + r1];
            frB[m] = fr_s[m * NPOLY + r1 + 6];
        }
#pragma unroll
        for (int co = 0; co < COH; ++co) {
            float rec = 0.f;
#pragma unroll
            for (int m = 0; m < MM; ++m) {
                rec = fmaf(lxs[wl1][m * CH + cob + co], frA[m], rec);
                rec = fmaf(lxs[wl1 - 1][m * CH + cob + co], frB[m], rec);
            }
            outv[co] = gelu_exact(acc[co] + rec);
        }
    }

    if constexpr (PAIR == 0) {
        if (vdB) {
            float* xnb = xout + (size_t)b * CH * LB_OUT + (size_t)cob * LB_OUT;
#pragma unroll
            for (int co = 0; co < COH; ++co)
                xnb[(size_t)co * LB_OUT + t0 + t] = outv[co];
        }
    } else {
        // fused final head: gelu(20->128) -> 128->1, sliced to 16384
        __syncthreads();   // all D reads of xs/lxs done
        if (vdB) {
#pragma unroll
            for (int co = 0; co < COH; ++co) xs[cob + co][t] = outv[co];
        }
        __syncthreads();   // layer-3 output visible in xs
        const bool vf = (t < TT2) && (t0 + t < LIN_);
        float* pb = &lxs[0][0];                    // lxs dead -> partial-sum buffer
        if (vf) {
            float xv[CH];
#pragma unroll
            for (int c = 0; c < CH; ++c) xv[c] = xs[c][t];
            const float* w11h  = w11 + (size_t)(half * 64) * CH;   // SGPR base
            const float* wouth = wout + half * 64;
            float partial = 0.f;
#pragma unroll 1
            for (int h = 0; h < 64; h += 2) {
                float hv0 = 0.f, hv1 = 0.f;
#pragma unroll
                for (int c = 0; c < CH; ++c) {
                    hv0 = fmaf(xv[c], w11h[h * CH + c], hv0);
                    hv1 = fmaf(xv[c], w11h[(h + 1) * CH + c], hv1);
                }
                partial = fmaf(gelu_exact(hv0), wouth[h], partial);
                partial = fmaf(gelu_exact(hv1), wouth[h + 1], partial);
            }
            pb[half * 256 + t] = partial;
        }
        __syncthreads();
        if (vf && half == 0)
            xout[(size_t)b * LIN_ + t0 + t] = pb[t] + pb[256 + t];
    }
}

extern "C" void kernel_launch(void* const* d_in, const int* in_sizes, int n_in,
                              void* d_out, int out_size, void* d_ws, size_t ws_size,
                              hipStream_t stream) {
    const float* input   = (const float*)d_in[0];
    const float* w_first = (const float*)d_in[1];
    const float* conv_a  = (const float*)d_in[2];
    const float* conv_b  = (const float*)d_in[3];
    const float* lin_m   = (const float*)d_in[4];
    const float* w11     = (const float*)d_in[5];
    const float* w_out   = (const float*)d_in[6];
    const float* filt_d  = (const float*)d_in[7];
    const float* filt_r  = (const float*)d_in[8];
    float* out = (float*)d_out;

    float* xA = (float*)d_ws;   // intermediate: layer-1 output, 32*20*16410 floats = 42 MB

    const int tiles = (LIN_ + TT2 - 1) / TT2 + ((16410 % TT2) ? 1 : 0) - ((16410 % TT2) ? 1 : 0); // 69
    {
        dim3 grid(( (L0 - 24) + TT2 - 1) / TT2, B_);   // 69 tiles covering 16410
        k_pair<0><<<grid, 512, 0, stream>>>(nullptr, xA, conv_a, conv_b, lin_m,
                                            filt_d, filt_r, input, w_first,
                                            nullptr, nullptr);
    }
    {
        dim3 grid((LIN_ + TT2 - 1) / TT2, B_);         // 69 tiles covering 16384
        k_pair<1><<<grid, 512, 0, stream>>>(xA, out, conv_a, conv_b, lin_m,
                                            filt_d, filt_r, nullptr, nullptr,
                                            w11, w_out);
    }
    (void)tiles;
}